// Round 1
// baseline (480.871 us; speedup 1.0000x reference)
//
#include <hip/hip_runtime.h>
#include <math.h>

// MessagePassingUnitGatingWithRelnessLogits fused kernel, MI355X (gfx950).
// N=32768 rows; D=1024 (paired=2048); A=256; FD=64; F8=8.
// Block = 16 rows, 256 threads (4 waves). Main GEMM via mfma_f32_16x16x32_bf16.

#define EPS_LN 1e-5f

typedef __attribute__((ext_vector_type(8))) short short8;   // 8 x bf16 (4 VGPRs)
typedef __attribute__((ext_vector_type(4))) float f32x4;    // MFMA accumulator

__device__ __forceinline__ unsigned short f2bf(float f) {
  unsigned int u = __float_as_uint(f);
  u += 0x7FFFu + ((u >> 16) & 1u);      // round-to-nearest-even
  return (unsigned short)(u >> 16);
}

__device__ __forceinline__ float wsum64(float v) {
  v += __shfl_xor(v, 32);
  v += __shfl_xor(v, 16);
  v += __shfl_xor(v, 8);
  v += __shfl_xor(v, 4);
  v += __shfl_xor(v, 2);
  v += __shfl_xor(v, 1);
  return v;
}

__device__ __forceinline__ float sigmoidf_(float x) {
  return 1.0f / (1.0f + __expf(-x));
}

// reverse_sigmoid forward: clip to [0.001,0.999], then logit
__device__ __forceinline__ float rsigf(float x) {
  float y = fminf(fmaxf(x, 0.001f), 0.999f);
  return logf(y) - log1pf(-y);
}

__device__ __forceinline__ ushort4 norm_pack(float4 x, float4 g, float4 b,
                                             float mu, float rstd) {
  ushort4 o;
  o.x = f2bf(fmaxf((x.x - mu) * rstd * g.x + b.x, 0.f));
  o.y = f2bf(fmaxf((x.y - mu) * rstd * g.y + b.y, 0.f));
  o.z = f2bf(fmaxf((x.z - mu) * rstd * g.z + b.z, 0.f));
  o.w = f2bf(fmaxf((x.w - mu) * rstd * g.w + b.w, 0.f));
  return o;
}

// ---------------------------------------------------------------------------
// Prep: W [2048][64] fp32 -> bf16 B-fragments in MFMA operand order.
// Layout: frag[((ntile*64 + kb)*64 + lane)*8 + j] = bf16(W[k][f]),
//   f = ntile*16 + (lane&15), k = kb*32 + (lane>>4)*8 + j.
// grid = 256 blocks (ntile*64+kb) x 64 threads.
// ---------------------------------------------------------------------------
__global__ void prep_wfrag(const float* __restrict__ W,
                           unsigned short* __restrict__ wfrag) {
  const int lane = threadIdx.x;
  const int b = blockIdx.x;
  const int ntile = b >> 6;
  const int kb = b & 63;
  const int f = (ntile << 4) + (lane & 15);
  const int kbase = (kb << 5) + ((lane >> 4) << 3);
  unsigned short tmp[8];
#pragma unroll
  for (int j = 0; j < 8; ++j) tmp[j] = f2bf(W[(size_t)(kbase + j) * 64 + f]);
  ushort4* dst = reinterpret_cast<ushort4*>(wfrag + (((size_t)b * 64 + lane) << 3));
  dst[0] = make_ushort4(tmp[0], tmp[1], tmp[2], tmp[3]);
  dst[1] = make_ushort4(tmp[4], tmp[5], tmp[6], tmp[7]);
}

// ---------------------------------------------------------------------------
// Main fused kernel.
// ---------------------------------------------------------------------------
__global__ void __launch_bounds__(256, 2) fused_main(
    const float* __restrict__ unary, const float* __restrict__ pair,
    const float* __restrict__ aux, const float* __restrict__ auxw,
    const float* __restrict__ ln_g, const float* __restrict__ ln_b,
    const float* __restrict__ b_lin,
    const float* __restrict__ ln_ag, const float* __restrict__ ln_ab,
    const float* __restrict__ W_aux, const float* __restrict__ b_aux,
    const float* __restrict__ gw, const float* __restrict__ agw,
    const unsigned short* __restrict__ wfrag,
    float* __restrict__ out, float* __restrict__ out_g) {
  // act: 16 rows x 2048 bf16, XOR-swizzled in 16B chunks to kill bank conflicts
  // on the MFMA A-frag reads (row-stride 4096B would alias to one bank).
  __shared__ unsigned short act_lds[16 * 2048];  // 64 KB

  const int tid = threadIdx.x;
  const int w = tid >> 6;     // wave 0..3
  const int lane = tid & 63;
  const int base = blockIdx.x << 4;

  float auxg0 = 0.f, auxg1 = 0.f, auxg2 = 0.f, auxg3 = 0.f;

  // ------------------- phase 1: LN + relu -> LDS (bf16); aux gate ----------
#pragma unroll
  for (int i = 0; i < 4; ++i) {
    const int rl = (w << 2) + i;         // local row 0..15
    const int row = base + rl;
    const int sw = rl & 7;

    const float4* u4 = reinterpret_cast<const float4*>(unary + (size_t)row * 1024);
    const float4* p4 = reinterpret_cast<const float4*>(pair + (size_t)row * 1024);
    float4 uv[4], pv[4];
#pragma unroll
    for (int j = 0; j < 4; ++j) {
      uv[j] = u4[lane + 64 * j];
      pv[j] = p4[lane + 64 * j];
    }
    float s = 0.f, sq = 0.f;
#pragma unroll
    for (int j = 0; j < 4; ++j) {
      uv[j].x = fmaxf(uv[j].x, 0.f); uv[j].y = fmaxf(uv[j].y, 0.f);
      uv[j].z = fmaxf(uv[j].z, 0.f); uv[j].w = fmaxf(uv[j].w, 0.f);
      pv[j].x = fmaxf(pv[j].x, 0.f); pv[j].y = fmaxf(pv[j].y, 0.f);
      pv[j].z = fmaxf(pv[j].z, 0.f); pv[j].w = fmaxf(pv[j].w, 0.f);
      s += uv[j].x + uv[j].y + uv[j].z + uv[j].w;
      s += pv[j].x + pv[j].y + pv[j].z + pv[j].w;
      sq += uv[j].x * uv[j].x + uv[j].y * uv[j].y + uv[j].z * uv[j].z + uv[j].w * uv[j].w;
      sq += pv[j].x * pv[j].x + pv[j].y * pv[j].y + pv[j].z * pv[j].z + pv[j].w * pv[j].w;
    }
    s = wsum64(s);
    sq = wsum64(sq);
    const float mu = s * (1.f / 2048.f);
    const float rstd = rsqrtf(sq * (1.f / 2048.f) - mu * mu + EPS_LN);

    const float4* g4 = reinterpret_cast<const float4*>(ln_g);
    const float4* bb4 = reinterpret_cast<const float4*>(ln_b);
#pragma unroll
    for (int j = 0; j < 4; ++j) {
      const int idx = lane + 64 * j;            // float4 index in the half-row
      const int off = (lane & 1) << 2;          // ushort offset inside chunk
      // unary half: k = 4*idx, chunk c = idx>>1
      ushort4 o = norm_pack(uv[j], g4[idx], bb4[idx], mu, rstd);
      int addr = (rl << 11) + ((((idx >> 1)) ^ sw) << 3) + off;
      *reinterpret_cast<ushort4*>(&act_lds[addr]) = o;
      // pair half: k = 1024 + 4*idx, chunk c = 128 + (idx>>1)
      ushort4 o2 = norm_pack(pv[j], g4[256 + idx], bb4[256 + idx], mu, rstd);
      int addr2 = (rl << 11) + (((128 + (idx >> 1)) ^ sw) << 3) + off;
      *reinterpret_cast<ushort4*>(&act_lds[addr2]) = o2;
    }

    // ---- aux gate for this row (A=256, F8=8, all fp32 VALU) ----
    const float4 av = reinterpret_cast<const float4*>(aux + (size_t)row * 256)[lane];
    float as = av.x + av.y + av.z + av.w;
    float asq = av.x * av.x + av.y * av.y + av.z * av.z + av.w * av.w;
    as = wsum64(as);
    asq = wsum64(asq);
    const float amu = as * (1.f / 256.f);
    const float arstd = rsqrtf(asq * (1.f / 256.f) - amu * amu + EPS_LN);
    const float4 ag = reinterpret_cast<const float4*>(ln_ag)[lane];
    const float4 ab = reinterpret_cast<const float4*>(ln_ab)[lane];
    float aa[4];
    aa[0] = fmaxf((av.x - amu) * arstd * ag.x + ab.x, 0.f);
    aa[1] = fmaxf((av.y - amu) * arstd * ag.y + ab.y, 0.f);
    aa[2] = fmaxf((av.z - amu) * arstd * ag.z + ab.z, 0.f);
    aa[3] = fmaxf((av.w - amu) * arstd * ag.w + ab.w, 0.f);
    float pf[8];
#pragma unroll
    for (int f = 0; f < 8; ++f) pf[f] = 0.f;
#pragma unroll
    for (int t = 0; t < 4; ++t) {
      const float4* wr = reinterpret_cast<const float4*>(W_aux + (((size_t)lane << 2) + t) * 8);
      float4 wa = wr[0], wb = wr[1];
      pf[0] += aa[t] * wa.x; pf[1] += aa[t] * wa.y;
      pf[2] += aa[t] * wa.z; pf[3] += aa[t] * wa.w;
      pf[4] += aa[t] * wb.x; pf[5] += aa[t] * wb.y;
      pf[6] += aa[t] * wb.z; pf[7] += aa[t] * wb.w;
    }
    float ss = 0.f;
#pragma unroll
    for (int f = 0; f < 8; ++f) {
      float v = wsum64(pf[f]);
      ss += sigmoidf_(v + b_aux[f]);
    }
    const float agv = ss * (1.f / 8.f);
    if (i == 0) auxg0 = agv;
    else if (i == 1) auxg1 = agv;
    else if (i == 2) auxg2 = agv;
    else auxg3 = agv;
  }

  __syncthreads();

  // ------------------- phase 2: [16x2048] @ [2048x16] per wave, MFMA -------
  f32x4 acc = {0.f, 0.f, 0.f, 0.f};
  const int arow = lane & 15;   // A row (m), also D col (n->f) index
  const int quad = lane >> 4;
  const int abase = arow << 11;
  const int asw = arow & 7;
  const unsigned short* wbase = wfrag + ((size_t)(w << 6) << 9);  // + kb*512 + lane*8
#pragma unroll 8
  for (int kb = 0; kb < 64; ++kb) {
    const int c = (kb << 2) + quad;
    const short8 afrag =
        *reinterpret_cast<const short8*>(&act_lds[abase + ((c ^ asw) << 3)]);
    const short8 bfrag =
        *reinterpret_cast<const short8*>(wbase + ((size_t)kb << 9) + (lane << 3));
    acc = __builtin_amdgcn_mfma_f32_16x16x32_bf16(afrag, bfrag, acc, 0, 0, 0);
  }

  // D layout: col(f) = lane&15 (+16w), row = quad*4 + reg.
  const float bl = b_lin[(w << 4) + arow];
  float sred[4];
#pragma unroll
  for (int i = 0; i < 4; ++i) {
    float v = sigmoidf_(acc[i] + bl);
    v += __shfl_xor(v, 1);
    v += __shfl_xor(v, 2);
    v += __shfl_xor(v, 4);
    v += __shfl_xor(v, 8);   // sum over the 16 f-cols of this wave's tile
    sred[i] = v;
  }

  __syncthreads();  // act_lds reads done -> reuse as float scratch
  float* gate_part = reinterpret_cast<float*>(act_lds);
  if (arow == 0) {
#pragma unroll
    for (int i = 0; i < 4; ++i)
      gate_part[(w << 4) + (quad << 2) + i] = sred[i];
  }
  __syncthreads();

  // ------------------- epilogue: combine gates, scale pair -----------------
  const float gwt = gw[0];
  const float agwt = agw[0];
#pragma unroll
  for (int i = 0; i < 4; ++i) {
    const int rl = (w << 2) + i;
    const int row = base + rl;
    const float gsum = gate_part[rl] + gate_part[16 + rl] +
                       gate_part[32 + rl] + gate_part[48 + rl];
    const float gate = gsum * (1.f / 64.f);
    const float auxg = (i == 0) ? auxg0 : (i == 1) ? auxg1 : (i == 2) ? auxg2 : auxg3;
    const float logit = gwt * rsigf(gate) + agwt * rsigf(auxg);
    const float g = sigmoidf_(logit) * auxw[row];

    const float4* p4 = reinterpret_cast<const float4*>(pair + (size_t)row * 1024);
    float4* o4 = reinterpret_cast<float4*>(out + (size_t)row * 1024);
#pragma unroll
    for (int j = 0; j < 4; ++j) {
      float4 pv = p4[lane + 64 * j];
      pv.x *= g; pv.y *= g; pv.z *= g; pv.w *= g;
      o4[lane + 64 * j] = pv;
    }
    if (lane == 0) out_g[row] = g;
  }
}

extern "C" void kernel_launch(void* const* d_in, const int* in_sizes, int n_in,
                              void* d_out, int out_size, void* d_ws, size_t ws_size,
                              hipStream_t stream) {
  const float* unary = (const float*)d_in[0];
  const float* pair  = (const float*)d_in[1];
  const float* aux   = (const float*)d_in[2];
  const float* auxw  = (const float*)d_in[3];
  const float* ln_g  = (const float*)d_in[4];
  const float* ln_b  = (const float*)d_in[5];
  const float* W     = (const float*)d_in[6];
  const float* b     = (const float*)d_in[7];
  const float* ln_ag = (const float*)d_in[8];
  const float* ln_ab = (const float*)d_in[9];
  const float* W_aux = (const float*)d_in[10];
  const float* b_aux = (const float*)d_in[11];
  const float* gw    = (const float*)d_in[12];
  const float* agw   = (const float*)d_in[13];

  const int N = in_sizes[3];            // 32768
  unsigned short* wfrag = (unsigned short*)d_ws;   // 256 KB bf16 W fragments
  float* out = (float*)d_out;
  float* out_g = out + (size_t)N * 1024;

  prep_wfrag<<<256, 64, 0, stream>>>(W, wfrag);
  fused_main<<<N / 16, 256, 0, stream>>>(unary, pair, aux, auxw, ln_g, ln_b, b,
                                         ln_ag, ln_ab, W_aux, b_aux, gw, agw,
                                         wfrag, out, out_g);
}